// Round 8
// baseline (182.324 us; speedup 1.0000x reference)
//
#include <hip/hip_runtime.h>
#include <hip/hip_bf16.h>

#define B_ 2
#define P_ 100000
#define CIN_ 23
#define C_ 64
#define H_ 512
#define W_ 512
#define S_ (H_*W_)       // 262144
#define NPT_ (B_*P_)     // 200000
#define NVOX_ (B_*S_)    // 524288

typedef __attribute__((ext_vector_type(8))) short short8;
typedef __attribute__((ext_vector_type(4))) float f32x4;
typedef __attribute__((ext_vector_type(4))) int i32x4;

__device__ inline unsigned short f2bf(float f) {
    union { __hip_bfloat16 h; unsigned short u; } cv;
    cv.h = __float2bfloat16(f);
    return cv.u;
}
__device__ inline float bf2f(unsigned short u) {
    union { unsigned int i; float f; } cv;
    cv.i = ((unsigned int)u) << 16;
    return cv.f;
}

// ---------------- Stage 1: histogram + occupied worklist ----------------
__global__ __launch_bounds__(256) void k_hist(
    const int* __restrict__ indices,
    const int* __restrict__ paddings,
    int* __restrict__ cnt,
    int* __restrict__ wl,
    int* __restrict__ wlcnt)
{
    int pt = blockIdx.x * 256 + threadIdx.x;
    if (pt >= NPT_) return;
    if (paddings[pt] != 0) return;
    int v = (pt / P_) * S_ + indices[pt];
    int old = atomicAdd(&cnt[v], 1);
    if (old == 0) {
        int slot = atomicAdd(wlcnt, 1);
        wl[slot] = v;
    }
}

// ---------------- Stage 2: exclusive-scan offsets (atomic block base) ----------------
// 512 blocks x 1024 elements; block base from global cursor (layout nondeterministic,
// per-voxel point SETS deterministic -> d_out deterministic)
__global__ __launch_bounds__(256) void k_offsets(
    const int* __restrict__ cnt,
    int* __restrict__ off,
    int* __restrict__ cur,
    int* __restrict__ gcursor)
{
    __shared__ int lds[256];
    __shared__ int sbase;
    int tid  = threadIdx.x;
    int base = blockIdx.x * 1024 + tid * 4;
    i32x4 c = *(const i32x4*)(cnt + base);
    int s1 = c[0] + c[1], s2 = s1 + c[2], s3 = s2 + c[3];
    lds[tid] = s3;
    __syncthreads();
    #pragma unroll
    for (int d = 1; d < 256; d <<= 1) {
        int v = (tid >= d) ? lds[tid - d] : 0;
        __syncthreads();
        if (tid >= d) lds[tid] += v;
        __syncthreads();
    }
    if (tid == 0) sbase = atomicAdd(gcursor, lds[255]);
    __syncthreads();
    int o = sbase + (tid == 0 ? 0 : lds[tid - 1]);
    i32x4 e;
    e[0] = o; e[1] = o + c[0]; e[2] = o + s1; e[3] = o + s2;
    *(i32x4*)(off + base) = e;
    *(i32x4*)(cur + base) = e;
}

// ---------------- Stage 3: scatter point ids into contiguous segments ----------------
__global__ __launch_bounds__(256) void k_scatter(
    const int* __restrict__ indices,
    const int* __restrict__ paddings,
    int* __restrict__ cur,
    int* __restrict__ ptid)
{
    int pt = blockIdx.x * 256 + threadIdx.x;
    if (pt >= NPT_) return;
    if (paddings[pt] != 0) return;
    int v = (pt / P_) * S_ + indices[pt];
    int slot = atomicAdd(&cur[v], 1);
    ptid[slot] = pt;
}

// ---------------- Stage 4: PointNet + max over occupied voxels (contiguous segs) ----
// one wave per 4 worklist entries; lane = channel; independent loads, no chains
__global__ __launch_bounds__(256) void k_voxel4s(
    const float* __restrict__ feat,
    const int* __restrict__ wl,
    const int* __restrict__ off,
    const int* __restrict__ cnt,
    const int* __restrict__ ptid,
    const float* __restrict__ w_pn,
    const float* __restrict__ g1, const float* __restrict__ b1,
    const float* __restrict__ m1, const float* __restrict__ v1,
    unsigned short* __restrict__ grid)          // bf16 [NVOX_][C_], occupied rows only
{
    int lane = threadIdx.x & 63;
    int wid  = __builtin_amdgcn_readfirstlane((blockIdx.x * 256 + threadIdx.x) >> 6);
    int e0   = wid * 4;

    int v0 = wl[e0];
    if (v0 < 0) return;                         // -1 tail contiguous
    int vx[4];
    vx[0] = v0; vx[1] = wl[e0 + 1]; vx[2] = wl[e0 + 2]; vx[3] = wl[e0 + 3];

    int n[4], base[4];
    #pragma unroll
    for (int i = 0; i < 4; ++i) {
        bool on = vx[i] >= 0;
        int vs  = on ? vx[i] : 0;
        n[i]    = on ? cnt[vs] : 0;
        base[i] = off[vs];
    }

    float w[CIN_];
    #pragma unroll
    for (int i = 0; i < CIN_; ++i) w[i] = w_pn[i * C_ + lane];

    int mn = max(max(n[0], n[1]), max(n[2], n[3]));
    float mx[4] = {-1e30f, -1e30f, -1e30f, -1e30f};

    for (int j = 0; j < mn; ++j) {
        const float* fp[4];
        float acc[4];
        #pragma unroll
        for (int i = 0; i < 4; ++i) {
            int jj = j < n[i] ? j : 0;
            int p  = ptid[base[i] + jj];        // scalar load (uniform addr)
            fp[i]  = feat + (size_t)p * CIN_;
            acc[i] = 0.f;
        }
        #pragma unroll
        for (int k = 0; k < CIN_; ++k)
            #pragma unroll
            for (int i = 0; i < 4; ++i) acc[i] += fp[i][k] * w[k];
        #pragma unroll
        for (int i = 0; i < 4; ++i)
            if (j < n[i]) mx[i] = fmaxf(mx[i], acc[i]);
    }

    float s   = g1[lane] * rsqrtf(v1[lane] + 1e-5f);
    float offv = b1[lane] - m1[lane] * s;
    #pragma unroll
    for (int i = 0; i < 4; ++i)
        if (vx[i] >= 0)
            grid[(size_t)vx[i] * C_ + lane] = f2bf(fmaxf(mx[i] * s + offv, 0.f));
}

// ---------------- Stage 5: 1x1 conv + BN2 + ReLU over occupied rows only ----------------
__global__ __launch_bounds__(256) void k_conv_occ(
    unsigned short* __restrict__ grid,      // bf16
    const int* __restrict__ wl,
    const float* __restrict__ conv_w,       // [out n][in k] f32
    const float* __restrict__ g2, const float* __restrict__ b2,
    const float* __restrict__ m2, const float* __restrict__ v2)
{
    int lane = threadIdx.x & 63;
    int wid  = (blockIdx.x * 256 + threadIdx.x) >> 6;
    int e0   = wid * 16;
    if (wl[e0] < 0) return;                 // whole tile past tail

    int row = lane & 15;
    int grp = lane >> 4;

    int vidr  = wl[e0 + row];
    int vsafe = vidr < 0 ? 0 : vidr;

    short8 bfrag[4][2];
    #pragma unroll
    for (int t = 0; t < 4; ++t)
        #pragma unroll
        for (int ks = 0; ks < 2; ++ks) {
            const float* wp = conv_w + (t * 16 + row) * 64 + ks * 32 + grp * 8;
            f32x4 lo = *(const f32x4*)(wp);
            f32x4 hi = *(const f32x4*)(wp + 4);
            short8 vv;
            #pragma unroll
            for (int j = 0; j < 4; ++j) {
                vv[j]     = (short)f2bf(lo[j]);
                vv[j + 4] = (short)f2bf(hi[j]);
            }
            bfrag[t][ks] = vv;
        }

    float sc[4], sh[4];
    #pragma unroll
    for (int t = 0; t < 4; ++t) {
        int nn  = t * 16 + row;
        float s = g2[nn] * rsqrtf(v2[nn] + 1e-3f);
        sc[t] = s;
        sh[t] = b2[nn] - m2[nn] * s;
    }

    const unsigned short* ap = grid + (size_t)vsafe * C_;
    short8 a[2];
    #pragma unroll
    for (int ks = 0; ks < 2; ++ks)
        a[ks] = *(const short8*)(ap + ks * 32 + grp * 8);

    f32x4 acc[4];
    #pragma unroll
    for (int t = 0; t < 4; ++t) acc[t] = (f32x4){0.f, 0.f, 0.f, 0.f};
    #pragma unroll
    for (int t = 0; t < 4; ++t) {
        acc[t] = __builtin_amdgcn_mfma_f32_16x16x32_bf16(a[0], bfrag[t][0], acc[t], 0, 0, 0);
        acc[t] = __builtin_amdgcn_mfma_f32_16x16x32_bf16(a[1], bfrag[t][1], acc[t], 0, 0, 0);
    }

    // C[m = grp*4+r][n = t*16+row]; junk A-rows only affect skipped C-rows
    #pragma unroll
    for (int r = 0; r < 4; ++r) {
        int vm = wl[e0 + grp * 4 + r];
        if (vm < 0) continue;
        unsigned short* op = grid + (size_t)vm * C_;
        #pragma unroll
        for (int t = 0; t < 4; ++t) {
            float val = fmaxf(acc[t][r] * sc[t] + sh[t], 0.f);
            op[t * 16 + row] = f2bf(val);
        }
    }
}

// ---------------- Stage 6: bilinear gather, 4 points/wave, empty->constant ----------------
__global__ __launch_bounds__(256) void k_gather4(
    const unsigned short* __restrict__ grid,
    const int* __restrict__ cnt,
    const float* __restrict__ vxyz,
    const float* __restrict__ g2, const float* __restrict__ b2,
    const float* __restrict__ m2, const float* __restrict__ v2,
    float* __restrict__ out)
{
    int lane = threadIdx.x & 63;
    int gw   = __builtin_amdgcn_readfirstlane((blockIdx.x * 256 + threadIdx.x) >> 6);
    int p0   = gw * 4;

    float s2  = g2[lane] * rsqrtf(v2[lane] + 1e-3f);
    float cst = fmaxf(b2[lane] - m2[lane] * s2, 0.f);   // conv(0)+BN2+ReLU row

    #pragma unroll
    for (int k = 0; k < 4; ++k) {
        int pt = p0 + k;                      // NPT_ % 4 == 0
        int b  = pt / P_;
        float xq = vxyz[(size_t)pt * 3 + 0];
        float yq = vxyz[(size_t)pt * 3 + 1];
        int x0 = (int)floorf(xq); x0 = min(max(x0, 0), W_ - 1);
        int x1 = min(x0 + 1, W_ - 1);
        int y0 = (int)floorf(yq); y0 = min(max(y0, 0), H_ - 1);
        int y1 = min(y0 + 1, H_ - 1);
        float x0f = (float)x0, x1f = (float)x1, y0f = (float)y0, y1f = (float)y1;
        float wa = (x1f - xq) * (y1f - yq);
        float wb = (x1f - xq) * (yq - y0f);
        float wc = (xq - x0f) * (y1f - yq);
        float wd = (xq - x0f) * (yq - y0f);

        int ia = y0 * W_ + x0, ib = y1 * W_ + x0, ic = y0 * W_ + x1, id = y1 * W_ + x1;
        const int* cb = cnt + (size_t)b * S_;
        const unsigned short* g = grid + (size_t)b * S_ * C_;
        int ca = cb[ia], cbv = cb[ib], cc = cb[ic], cd = cb[id];
        float Ia = ca  > 0 ? bf2f(g[(size_t)ia * C_ + lane]) : cst;
        float Ib = cbv > 0 ? bf2f(g[(size_t)ib * C_ + lane]) : cst;
        float Ic = cc  > 0 ? bf2f(g[(size_t)ic * C_ + lane]) : cst;
        float Id = cd  > 0 ? bf2f(g[(size_t)id * C_ + lane]) : cst;

        out[(size_t)pt * C_ + lane] = wa * Ia + wb * Ib + wc * Ic + wd * Id;
    }
}

extern "C" void kernel_launch(void* const* d_in, const int* in_sizes, int n_in,
                              void* d_out, int out_size, void* d_ws, size_t ws_size,
                              hipStream_t stream)
{
    const float* feat     = (const float*)d_in[1];
    const int*   indices  = (const int*)d_in[3];
    const int*   paddings = (const int*)d_in[4];
    const float* vxyz     = (const float*)d_in[5];
    const float* w_pn     = (const float*)d_in[6];
    const float* g1       = (const float*)d_in[7];
    const float* b1       = (const float*)d_in[8];
    const float* m1       = (const float*)d_in[9];
    const float* v1       = (const float*)d_in[10];
    const float* cw       = (const float*)d_in[11];
    const float* g2       = (const float*)d_in[12];
    const float* b2       = (const float*)d_in[13];
    const float* m2       = (const float*)d_in[14];
    const float* v2       = (const float*)d_in[15];

    // ws layout (16B-aligned regions):
    // grid 67.1MB | cnt 2MB | off 2MB | cur 2MB | wl 0.8MB | ptid 0.8MB | ctrs 8B
    char* p = (char*)d_ws;
    unsigned short* grid = (unsigned short*)p;  p += (size_t)NVOX_ * C_ * 2;
    int* cnt  = (int*)p;  p += (size_t)NVOX_ * 4;
    int* off  = (int*)p;  p += (size_t)NVOX_ * 4;
    int* cur  = (int*)p;  p += (size_t)NVOX_ * 4;
    int* wl   = (int*)p;  p += (size_t)NPT_ * 4;
    int* ptid = (int*)p;  p += (size_t)NPT_ * 4;
    int* ctrs = (int*)p;                        // [0]=gcursor [1]=wlcnt

    hipMemsetAsync(cnt, 0, (size_t)NVOX_ * 4, stream);
    hipMemsetAsync(wl, 0xFF, (size_t)NPT_ * 4, stream);
    hipMemsetAsync(ctrs, 0, 8, stream);

    k_hist<<<(NPT_ + 255) / 256, 256, 0, stream>>>(indices, paddings, cnt, wl, ctrs + 1);

    k_offsets<<<NVOX_ / 1024, 256, 0, stream>>>(cnt, off, cur, ctrs);

    k_scatter<<<(NPT_ + 255) / 256, 256, 0, stream>>>(indices, paddings, cur, ptid);

    // ceil(NPT_/4) = 50000 waves -> 12500 blocks
    k_voxel4s<<<12500, 256, 0, stream>>>(
        feat, wl, off, cnt, ptid, w_pn, g1, b1, m1, v1, grid);

    // ceil(NPT_/16) = 12500 waves -> 3125 blocks
    k_conv_occ<<<3125, 256, 0, stream>>>(grid, wl, cw, g2, b2, m2, v2);

    // 50000 waves -> 12500 blocks
    k_gather4<<<12500, 256, 0, stream>>>(
        grid, cnt, vxyz, g2, b2, m2, v2, (float*)d_out);
}

// Round 9
// 146.479 us; speedup vs baseline: 1.2447x; 1.2447x over previous
//
#include <hip/hip_runtime.h>
#include <hip/hip_bf16.h>

#define B_ 2
#define P_ 100000
#define CIN_ 23
#define C_ 64
#define H_ 512
#define W_ 512
#define S_ (H_*W_)       // 262144
#define NPT_ (B_*P_)     // 200000
#define NVOX_ (B_*S_)    // 524288

typedef __attribute__((ext_vector_type(8))) short short8;
typedef __attribute__((ext_vector_type(4))) float f32x4;

__device__ inline unsigned short f2bf(float f) {
    union { __hip_bfloat16 h; unsigned short u; } cv;
    cv.h = __float2bfloat16(f);
    return cv.u;
}
__device__ inline float bf2f(unsigned short u) {
    union { unsigned int i; float f; } cv;
    cv.i = ((unsigned int)u) << 16;
    return cv.f;
}

// ---------------- Stage 1: build per-voxel linked lists ----------------
__global__ __launch_bounds__(256) void k_fill(
    const int* __restrict__ indices,
    const int* __restrict__ paddings,
    int* __restrict__ head,
    int* __restrict__ next)
{
    int pt = blockIdx.x * 256 + threadIdx.x;
    if (pt >= NPT_) return;
    if (paddings[pt] != 0) return;              // padded -> dropped
    int v = (pt / P_) * S_ + indices[pt];
    int old = atomicExch(&head[v], pt);
    next[pt] = old;
}

// ---------------- Stage 2: dense PointNet dot (pre-BN), coalesced ----------------
// lane = channel, 8 points per wave; z[pt][c] bf16 (rounding before max is exact:
// max is monotone under bf16 quantization)
__global__ __launch_bounds__(256) void k_z(
    const float* __restrict__ feat,
    const float* __restrict__ w_pn,
    unsigned short* __restrict__ z)
{
    int lane = threadIdx.x & 63;
    int wid  = (blockIdx.x * 256 + threadIdx.x) >> 6;
    int p0   = wid * 8;                         // NPT_ % 8 == 0
    if (p0 >= NPT_) return;

    float w[CIN_];
    #pragma unroll
    for (int i = 0; i < CIN_; ++i) w[i] = w_pn[i * C_ + lane];

    #pragma unroll
    for (int i = 0; i < 8; ++i) {
        int pt = p0 + i;
        const float* f = feat + (size_t)pt * CIN_;   // wave-uniform -> scalar loads
        float acc = 0.f;
        #pragma unroll
        for (int k = 0; k < CIN_; ++k) acc += f[k] * w[k];
        z[(size_t)pt * C_ + lane] = f2bf(acc);
    }
}

// ---------------- Stage 3: segment-max walk, 8 voxels per wave ----------------
// loop body = 8 independent 128B vector loads + fmax (no FMAs); writes whole grid
// (empty voxel: mx=-1e30 -> relu(mx*s+off)==0 exactly)
__global__ __launch_bounds__(256) void k_seg8(
    const unsigned short* __restrict__ z,
    const int* __restrict__ head,
    const int* __restrict__ next,
    const float* __restrict__ g1, const float* __restrict__ b1,
    const float* __restrict__ m1, const float* __restrict__ v1,
    unsigned short* __restrict__ grid)          // bf16 [NVOX_][C_]
{
    int lane = threadIdx.x & 63;
    int q    = (blockIdx.x * 256 + threadIdx.x) >> 6;
    int v0   = q * 8;                           // < NVOX_ (NVOX_/8 waves)

    int pc[8];
    #pragma unroll
    for (int i = 0; i < 8; ++i)
        pc[i] = __builtin_amdgcn_readfirstlane(head[v0 + i]);

    float mx[8];
    #pragma unroll
    for (int i = 0; i < 8; ++i) mx[i] = -1e30f;

    bool any = false;
    #pragma unroll
    for (int i = 0; i < 8; ++i) any |= (pc[i] >= 0);

    while (any) {
        float zz[8];
        int   nx[8];
        #pragma unroll
        for (int i = 0; i < 8; ++i) {
            int p  = pc[i] < 0 ? 0 : pc[i];
            zz[i]  = bf2f(z[(size_t)p * C_ + lane]);           // 128B vector load
            nx[i]  = pc[i] < 0 ? -1
                   : __builtin_amdgcn_readfirstlane(next[pc[i]]);
        }
        #pragma unroll
        for (int i = 0; i < 8; ++i) {
            if (pc[i] >= 0) mx[i] = fmaxf(mx[i], zz[i]);
            pc[i] = pc[i] < 0 ? -1 : nx[i];
        }
        any = false;
        #pragma unroll
        for (int i = 0; i < 8; ++i) any |= (pc[i] >= 0);
    }

    float s   = g1[lane] * rsqrtf(v1[lane] + 1e-5f);
    float off = b1[lane] - m1[lane] * s;
    #pragma unroll
    for (int i = 0; i < 8; ++i)
        grid[(size_t)(v0 + i) * C_ + lane] = f2bf(fmaxf(mx[i] * s + off, 0.f));
}

// ---------------- Stage 4: 1x1 conv (64x64) + BN2 + ReLU, in place, MFMA ----------------
// one wave per FOUR 16-voxel tiles
__global__ __launch_bounds__(256) void k_conv(
    unsigned short* __restrict__ grid,      // bf16
    const float* __restrict__ conv_w,       // [out n][in k] f32
    const float* __restrict__ g2, const float* __restrict__ b2,
    const float* __restrict__ m2, const float* __restrict__ v2)
{
    int lane = threadIdx.x & 63;
    int wv   = (blockIdx.x * 256 + threadIdx.x) >> 6;   // 0..8191
    int row  = lane & 15;       // A-row / B-col / C-col
    int grp  = lane >> 4;       // k-group

    // B fragments: lane holds B[k = ks*32 + grp*8 + j][n = t*16 + row] = W[n][k]
    short8 bfrag[4][2];
    #pragma unroll
    for (int t = 0; t < 4; ++t)
        #pragma unroll
        for (int ks = 0; ks < 2; ++ks) {
            const float* wp = conv_w + (t * 16 + row) * 64 + ks * 32 + grp * 8;
            f32x4 lo = *(const f32x4*)(wp);
            f32x4 hi = *(const f32x4*)(wp + 4);
            short8 vv;
            #pragma unroll
            for (int j = 0; j < 4; ++j) {
                vv[j]     = (short)f2bf(lo[j]);
                vv[j + 4] = (short)f2bf(hi[j]);
            }
            bfrag[t][ks] = vv;
        }

    float sc[4], sh[4];
    #pragma unroll
    for (int t = 0; t < 4; ++t) {
        int n   = t * 16 + row;
        float s = g2[n] * rsqrtf(v2[n] + 1e-3f);
        sc[t] = s;
        sh[t] = b2[n] - m2[n] * s;
    }

    #pragma unroll
    for (int sub = 0; sub < 4; ++sub) {
        unsigned short* gp = grid + ((size_t)wv * 4 + sub) * 16 * 64;

        short8 a[2];
        #pragma unroll
        for (int ks = 0; ks < 2; ++ks)
            a[ks] = *(const short8*)(gp + row * 64 + ks * 32 + grp * 8);

        f32x4 acc[4];
        #pragma unroll
        for (int t = 0; t < 4; ++t) acc[t] = (f32x4){0.f, 0.f, 0.f, 0.f};
        #pragma unroll
        for (int t = 0; t < 4; ++t) {
            acc[t] = __builtin_amdgcn_mfma_f32_16x16x32_bf16(a[0], bfrag[t][0], acc[t], 0, 0, 0);
            acc[t] = __builtin_amdgcn_mfma_f32_16x16x32_bf16(a[1], bfrag[t][1], acc[t], 0, 0, 0);
        }

        // epilogue: C[m = grp*4+r][n = t*16+row], BN2+ReLU, bf16 store in place
        #pragma unroll
        for (int t = 0; t < 4; ++t)
            #pragma unroll
            for (int r = 0; r < 4; ++r) {
                float val = fmaxf(acc[t][r] * sc[t] + sh[t], 0.f);
                gp[(grp * 4 + r) * 64 + t * 16 + row] = f2bf(val);
            }
    }
}

// ---------------- Stage 5: bilinear gather, 4 points per wave ----------------
// im[b,x,y] = v[b,y,x] -> voxel id = y*W + x ; lane = channel
__global__ __launch_bounds__(256) void k_gather4(
    const unsigned short* __restrict__ grid,   // bf16, dense final values
    const float* __restrict__ vxyz,
    float* __restrict__ out)                   // f32 output
{
    int lane = threadIdx.x & 63;
    int gw   = (blockIdx.x * 256 + threadIdx.x) >> 6;
    int p0   = gw * 4;                          // NPT_ % 4 == 0
    if (p0 >= NPT_) return;

    #pragma unroll
    for (int k = 0; k < 4; ++k) {
        int pt = p0 + k;
        int b  = pt / P_;
        float xq = vxyz[(size_t)pt * 3 + 0];
        float yq = vxyz[(size_t)pt * 3 + 1];
        int x0 = (int)floorf(xq); x0 = min(max(x0, 0), W_ - 1);
        int x1 = min(x0 + 1, W_ - 1);
        int y0 = (int)floorf(yq); y0 = min(max(y0, 0), H_ - 1);
        int y1 = min(y0 + 1, H_ - 1);
        float x0f = (float)x0, x1f = (float)x1, y0f = (float)y0, y1f = (float)y1;
        float wa = (x1f - xq) * (y1f - yq);
        float wb = (x1f - xq) * (yq - y0f);
        float wc = (xq - x0f) * (y1f - yq);
        float wd = (xq - x0f) * (yq - y0f);

        const unsigned short* g = grid + (size_t)b * S_ * C_;
        float Ia = bf2f(g[(size_t)(y0 * W_ + x0) * C_ + lane]);
        float Ib = bf2f(g[(size_t)(y1 * W_ + x0) * C_ + lane]);
        float Ic = bf2f(g[(size_t)(y0 * W_ + x1) * C_ + lane]);
        float Id = bf2f(g[(size_t)(y1 * W_ + x1) * C_ + lane]);

        out[(size_t)pt * C_ + lane] = wa * Ia + wb * Ib + wc * Ic + wd * Id;
    }
}

extern "C" void kernel_launch(void* const* d_in, const int* in_sizes, int n_in,
                              void* d_out, int out_size, void* d_ws, size_t ws_size,
                              hipStream_t stream)
{
    const float* feat     = (const float*)d_in[1];
    const int*   indices  = (const int*)d_in[3];
    const int*   paddings = (const int*)d_in[4];
    const float* vxyz     = (const float*)d_in[5];
    const float* w_pn     = (const float*)d_in[6];
    const float* g1       = (const float*)d_in[7];
    const float* b1       = (const float*)d_in[8];
    const float* m1       = (const float*)d_in[9];
    const float* v1       = (const float*)d_in[10];
    const float* cw       = (const float*)d_in[11];
    const float* g2       = (const float*)d_in[12];
    const float* b2       = (const float*)d_in[13];
    const float* m2       = (const float*)d_in[14];
    const float* v2       = (const float*)d_in[15];

    // ws layout: grid bf16 67.1MB | z bf16 25.6MB | head 2.1MB | next 0.8MB  (< 134MB proven)
    char* p = (char*)d_ws;
    unsigned short* grid = (unsigned short*)p;  p += (size_t)NVOX_ * C_ * 2;
    unsigned short* z    = (unsigned short*)p;  p += (size_t)NPT_ * C_ * 2;
    int* head = (int*)p;  p += (size_t)NVOX_ * 4;
    int* next = (int*)p;

    hipMemsetAsync(head, 0xFF, (size_t)NVOX_ * 4, stream);   // head = -1

    k_fill<<<(NPT_ + 255) / 256, 256, 0, stream>>>(indices, paddings, head, next);

    // 25000 waves -> 6250 blocks
    k_z<<<6250, 256, 0, stream>>>(feat, w_pn, z);

    // NVOX_/8 = 65536 waves -> 16384 blocks
    k_seg8<<<16384, 256, 0, stream>>>(z, head, next, g1, b1, m1, v1, grid);

    // 8192 waves x 4 tiles -> 2048 blocks
    k_conv<<<2048, 256, 0, stream>>>(grid, cw, g2, b2, m2, v2);

    // 50000 waves -> 12500 blocks
    k_gather4<<<12500, 256, 0, stream>>>(grid, vxyz, (float*)d_out);
}